// Round 6
// baseline (98.729 us; speedup 1.0000x reference)
//
#include <hip/hip_runtime.h>
#include <stdint.h>

#define BB 8
#define NN 2048
#define CC 128
#define OO 128

typedef __attribute__((ext_vector_type(8))) short bf16x8;
typedef __attribute__((ext_vector_type(4))) float f32x4;
typedef __attribute__((ext_vector_type(4))) int i32x4;
typedef __attribute__((ext_vector_type(4))) unsigned int u32x4;
typedef __attribute__((ext_vector_type(4))) unsigned short u16x4;
typedef unsigned int u32;
typedef unsigned short u16;

__device__ __forceinline__ u16 f2bf(float f) {
    union { float f; u32 u; } v; v.f = f;
    u32 r = v.u + 0x7FFFu + ((v.u >> 16) & 1u);
    return (u16)(r >> 16);
}
// pack two f32 -> one u32 of 2 bf16 (round-half-up; 1 ulp from RNE at ties only)
__device__ __forceinline__ u32 pkbf(float a, float b) {
    union { float f; u32 u; } x, y; x.f = a; y.f = b;
    return ((x.u + 0x8000u) >> 16) | ((y.u + 0x8000u) & 0xFFFF0000u);
}

// ---------------------------------------------------------------------------
// Kernel 0: Wt[o][c] = bf16(W_lin[c][o]).  16 blocks x 256 thr (tiny).
// ---------------------------------------------------------------------------
__global__ __launch_bounds__(256) void wt_kernel(
    const float* __restrict__ W_lin, u16* __restrict__ Wt)
{
    __shared__ float ws2[8][132];
    const int t = threadIdx.x, o0 = blockIdx.x * 8;
    f32x4 v = *(const f32x4*)(W_lin + (t >> 1) * OO + o0 + (t & 1) * 4);
    #pragma unroll
    for (int e = 0; e < 4; ++e) ws2[(t & 1) * 4 + e][t >> 1] = v[e];
    __syncthreads();
    const int oo = t >> 5, c0 = (t & 31) * 4;
    f32x4 u = *(const f32x4*)&ws2[oo][c0];
    u16x4 h;
    #pragma unroll
    for (int e = 0; e < 4; ++e) h[e] = f2bf(u[e]);
    *(u16x4*)(Wt + (size_t)(o0 + oo) * CC + c0) = h;
}

// ---------------------------------------------------------------------------
// Kernel 1: precompute via MFMA, no LDS.
//   sj[b][n] = x·w1 + b_fc ; sk[b][n] = x·w2 (f32); Yt = bf16((x@W_lin)^T)
// ---------------------------------------------------------------------------
__global__ __launch_bounds__(256) void precompute_kernel(
    const float* __restrict__ x, const float* __restrict__ W_fc,
    const float* __restrict__ b_fc, const u16* __restrict__ Wt,
    float* __restrict__ sj, float* __restrict__ sk, u16* __restrict__ Yt)
{
    const int t = threadIdx.x, l = t & 63, w = t >> 6;
    const int sl = l & 15, g = l >> 4;
    const int b  = blockIdx.x >> 6;
    const int k0 = (blockIdx.x & 63) << 5;
    const int mt = w & 1, nb = (w >> 1) << 2;
    const int row = k0 + mt * 16 + sl;
    const float* xr = x + ((size_t)(b * NN + row) << 7);

    bf16x8 a[4];
    float p1 = 0.f, p2 = 0.f;
    #pragma unroll
    for (int ks = 0; ks < 4; ++ks) {
        f32x4 lo4 = *(const f32x4*)(xr + ks * 32 + g * 8);
        f32x4 hi4 = *(const f32x4*)(xr + ks * 32 + g * 8 + 4);
        f32x4 w1l = *(const f32x4*)(W_fc + ks * 32 + g * 8);
        f32x4 w1h = *(const f32x4*)(W_fc + ks * 32 + g * 8 + 4);
        f32x4 w2l = *(const f32x4*)(W_fc + CC + ks * 32 + g * 8);
        f32x4 w2h = *(const f32x4*)(W_fc + CC + ks * 32 + g * 8 + 4);
        bf16x8 av;
        #pragma unroll
        for (int e = 0; e < 4; ++e) {
            p1 += lo4[e] * w1l[e] + hi4[e] * w1h[e];
            p2 += lo4[e] * w2l[e] + hi4[e] * w2h[e];
            av[e]     = (short)f2bf(lo4[e]);
            av[e + 4] = (short)f2bf(hi4[e]);
        }
        a[ks] = av;
    }
    p1 += __shfl_xor(p1, 16); p1 += __shfl_xor(p1, 32);
    p2 += __shfl_xor(p2, 16); p2 += __shfl_xor(p2, 32);
    if (w < 2 && g == 0) {
        sj[b * NN + row] = p1 + b_fc[0];
        sk[b * NN + row] = p2;
    }

    f32x4 acc[4];
    #pragma unroll
    for (int i = 0; i < 4; ++i) acc[i] = (f32x4){0.f, 0.f, 0.f, 0.f};
    #pragma unroll
    for (int i = 0; i < 4; ++i) {
        const u16* wp = Wt + (size_t)((nb + i) * 16 + sl) * CC;
        #pragma unroll
        for (int ks = 0; ks < 4; ++ks) {
            bf16x8 bv = *(const bf16x8*)(wp + ks * 32 + g * 8);
            acc[i] = __builtin_amdgcn_mfma_f32_16x16x32_bf16(a[ks], bv, acc[i], 0, 0, 0);
        }
    }
    #pragma unroll
    for (int i = 0; i < 4; ++i) {
        const int o = (nb + i) * 16 + sl;
        u16x4 h;
        #pragma unroll
        for (int e = 0; e < 4; ++e) h[e] = f2bf(acc[i][e]);
        *(u16x4*)(Yt + (size_t)(b * OO + o) * NN + k0 + mt * 16 + g * 4) = h;
    }
}

// ---------------------------------------------------------------------------
// Kernel 2: main aggregation — fully independent single-wave blocks.
// NO LDS, NO barriers, NO inline asm. Each wave owns 16 j-rows x all 128 o:
//   - lane l computes its OWN A-fragment sigmoids: P[j0+sw][k=kk*32+kg*8+e]
//     (sigmoid computed exactly once per (j,k) — j-split, not o-split)
//   - adj register-prefetched 2 tiles ahead into static E/O sets
//   - B streamed from L2/L1-resident Yt[b] with immediate-offset loads,
//     interleaved with MFMA by the compiler (no fences to defeat it)
//   - rowsum via 2 shuffles; epilogue broadcast via __shfl
// grid = 1024 blocks x 64 thr; b = bid&7 (XCD-pinned; ~4 same-b waves/CU
// share the 32KB B k-tile through L1).
// ---------------------------------------------------------------------------
__global__ __launch_bounds__(64) void graphconv_main(
    const int* __restrict__ adj, const float* __restrict__ sj,
    const float* __restrict__ sk, const u16* __restrict__ Yt,
    const float* __restrict__ b_lin, float* __restrict__ out)
{
    const int l  = threadIdx.x;
    const int sw = l & 15, kg = l >> 4;
    const int b  = blockIdx.x & 7;
    const int j0 = (int)(blockIdx.x >> 3) << 4;

    const float sjr = sj[b * NN + j0 + sw];
    const int*   arow = adj + ((size_t)b * NN + j0 + sw) * NN + kg * 8;
    const float* skb  = sk + b * NN + kg * 8;

    // per-ot B base pointers; kt*256B + kk*64B fits the 13-bit imm offset
    const u16* yb[8];
    #pragma unroll
    for (int ot = 0; ot < 8; ++ot)
        yb[ot] = Yt + (size_t)(b * OO + ot * 16 + sw) * NN + kg * 8;

    f32x4 acc[8];
    #pragma unroll
    for (int ot = 0; ot < 8; ++ot) acc[ot] = (f32x4){0.f, 0.f, 0.f, 0.f};
    float psum = 0.f;

    // adj E/O register sets (static, no rotation)
    i32x4 aE[8], aO[8];
    #pragma unroll
    for (int q = 0; q < 4; ++q) {
        aE[2*q]   = *(const i32x4*)(arow + q * 32);
        aE[2*q+1] = *(const i32x4*)(arow + q * 32 + 4);
    }
    #pragma unroll
    for (int q = 0; q < 4; ++q) {
        aO[2*q]   = *(const i32x4*)(arow + 128 + q * 32);
        aO[2*q+1] = *(const i32x4*)(arow + 128 + q * 32 + 4);
    }

#define TILE(KT, AV)                                                          \
    {                                                                         \
        const int kt_ = (KT);                                                 \
        /* sk for this tile (L1-resident, 8KB/batch) */                       \
        f32x4 sv[8];                                                          \
        _Pragma("unroll")                                                     \
        for (int q = 0; q < 4; ++q) {                                         \
            sv[2*q]   = *(const f32x4*)(skb + kt_ * 128 + q * 32);            \
            sv[2*q+1] = *(const f32x4*)(skb + kt_ * 128 + q * 32 + 4);        \
        }                                                                     \
        /* A-fragments: P[j0+sw][kt*128 + q*32 + kg*8 + e] directly */        \
        bf16x8 af[4];                                                         \
        _Pragma("unroll")                                                     \
        for (int q = 0; q < 4; ++q) {                                         \
            float pv[8];                                                      \
            _Pragma("unroll")                                                 \
            for (int h = 0; h < 2; ++h) {                                     \
                i32x4 a4 = AV[2*q+h];                                         \
                f32x4 s4 = sv[2*q+h];                                         \
                _Pragma("unroll")                                             \
                for (int e = 0; e < 4; ++e) {                                 \
                    float z  = sjr + s4[e];                                   \
                    float sg = __builtin_amdgcn_rcpf(1.0f + __expf(-z));      \
                    float p  = a4[e] ? sg : 0.0f;                             \
                    psum += p;                                                \
                    pv[h*4+e] = p;                                            \
                }                                                             \
            }                                                                 \
            u32 w0 = pkbf(pv[0], pv[1]), w1 = pkbf(pv[2], pv[3]);             \
            u32 w2 = pkbf(pv[4], pv[5]), w3 = pkbf(pv[6], pv[7]);             \
            af[q] = __builtin_bit_cast(bf16x8, (u32x4){w0, w1, w2, w3});      \
        }                                                                     \
        /* adj(kt+2) prefetch into the now-dead set (slack ~2 tiles) */       \
        if (kt_ < 14) {                                                       \
            _Pragma("unroll")                                                 \
            for (int q = 0; q < 4; ++q) {                                     \
                AV[2*q]   = *(const i32x4*)(arow + (kt_+2) * 128 + q * 32);   \
                AV[2*q+1] = *(const i32x4*)(arow + (kt_+2) * 128 + q * 32 + 4); \
            }                                                                 \
        }                                                                     \
        /* B stream + MFMA (compiler-scheduled, no fences) */                 \
        _Pragma("unroll")                                                     \
        for (int ot = 0; ot < 8; ++ot) {                                      \
            const u16* yp = yb[ot] + kt_ * 128;                               \
            bf16x8 b0 = *(const bf16x8*)(yp);                                 \
            bf16x8 b1 = *(const bf16x8*)(yp + 32);                            \
            bf16x8 b2 = *(const bf16x8*)(yp + 64);                            \
            bf16x8 b3 = *(const bf16x8*)(yp + 96);                            \
            acc[ot] = __builtin_amdgcn_mfma_f32_16x16x32_bf16(af[0], b0, acc[ot], 0, 0, 0); \
            acc[ot] = __builtin_amdgcn_mfma_f32_16x16x32_bf16(af[1], b1, acc[ot], 0, 0, 0); \
            acc[ot] = __builtin_amdgcn_mfma_f32_16x16x32_bf16(af[2], b2, acc[ot], 0, 0, 0); \
            acc[ot] = __builtin_amdgcn_mfma_f32_16x16x32_bf16(af[3], b3, acc[ot], 0, 0, 0); \
        }                                                                     \
    }

    for (int m = 0; m < 8; ++m) {
        TILE(2 * m,     aE)
        TILE(2 * m + 1, aO)
    }
#undef TILE

    // rowsum: lane covers row sw, k-slots (k%32)/8==kg -> reduce over kg
    float s = psum;
    s += __shfl_xor(s, 16);
    s += __shfl_xor(s, 32);   // now every lane holds sum of row (l&15)
    float rinv[4];
    #pragma unroll
    for (int i = 0; i < 4; ++i)
        rinv[i] = 1.0f / __shfl(s, kg * 4 + i);

    // epilogue: C[j = j0 + kg*4 + i][o = ot*16 + sw]
    #pragma unroll
    for (int ot = 0; ot < 8; ++ot) {
        const int col = ot * 16 + sw;
        const float bl = b_lin[col];
        #pragma unroll
        for (int i = 0; i < 4; ++i)
            out[(size_t)(b * NN + j0 + kg * 4 + i) * OO + col] = acc[ot][i] * rinv[i] + bl;
    }
}

extern "C" void kernel_launch(void* const* d_in, const int* in_sizes, int n_in,
                              void* d_out, int out_size, void* d_ws, size_t ws_size,
                              hipStream_t stream) {
    const float* x     = (const float*)d_in[0];
    const int*   adj   = (const int*)d_in[1];
    const float* W_fc  = (const float*)d_in[2];
    const float* b_fc  = (const float*)d_in[3];
    const float* W_lin = (const float*)d_in[4];
    const float* b_lin = (const float*)d_in[5];
    float* out = (float*)d_out;

    // workspace: Yt (bf16, 4MB) | sj (64KB) | sk (64KB) | Wt (32KB)
    u16*   Yt = (u16*)d_ws;
    float* sj = (float*)((char*)d_ws + (size_t)BB * OO * NN * sizeof(u16));
    float* sk = sj + BB * NN;
    u16*   Wt = (u16*)(sk + BB * NN);

    wt_kernel<<<16, 256, 0, stream>>>(W_lin, Wt);
    precompute_kernel<<<512, 256, 0, stream>>>(x, W_fc, b_fc, Wt, sj, sk, Yt);
    graphconv_main<<<1024, 64, 0, stream>>>(adj, sj, sk, Yt, b_lin, out);
}

// Round 7
// 66.585 us; speedup vs baseline: 1.4827x; 1.4827x over previous
//
#include <hip/hip_runtime.h>
#include <stdint.h>

#define BB 8
#define NN 2048
#define CC 128
#define OO 128

typedef __attribute__((ext_vector_type(8))) short bf16x8;
typedef __attribute__((ext_vector_type(4))) float f32x4;
typedef __attribute__((ext_vector_type(4))) int i32x4;
typedef __attribute__((ext_vector_type(4))) unsigned int u32x4;
typedef __attribute__((ext_vector_type(4))) unsigned short u16x4;
typedef unsigned int u32;
typedef unsigned short u16;

__device__ __forceinline__ u16 f2bf(float f) {
    union { float f; u32 u; } v; v.f = f;
    u32 r = v.u + 0x7FFFu + ((v.u >> 16) & 1u);
    return (u16)(r >> 16);
}
// pack two f32 -> u32 of 2 bf16 (round-half-up)
__device__ __forceinline__ u32 pkbf(float a, float b) {
    union { float f; u32 u; } x, y; x.f = a; y.f = b;
    return ((x.u + 0x8000u) >> 16) | ((y.u + 0x8000u) & 0xFFFF0000u);
}
__device__ __forceinline__ void gl_lds16(const u16* g, u16* l) {
    __builtin_amdgcn_global_load_lds(
        (__attribute__((address_space(1))) void*)(uintptr_t)g,
        (__attribute__((address_space(3))) void*)l, 16, 0, 0);
}

// ---------------------------------------------------------------------------
// Kernel 0: Wt[o][c] = bf16(W_lin[c][o]).
// ---------------------------------------------------------------------------
__global__ __launch_bounds__(256) void wt_kernel(
    const float* __restrict__ W_lin, u16* __restrict__ Wt)
{
    __shared__ float ws2[8][132];
    const int t = threadIdx.x, o0 = blockIdx.x * 8;
    f32x4 v = *(const f32x4*)(W_lin + (t >> 1) * OO + o0 + (t & 1) * 4);
    #pragma unroll
    for (int e = 0; e < 4; ++e) ws2[(t & 1) * 4 + e][t >> 1] = v[e];
    __syncthreads();
    const int oo = t >> 5, c0 = (t & 31) * 4;
    f32x4 u = *(const f32x4*)&ws2[oo][c0];
    u16x4 h;
    #pragma unroll
    for (int e = 0; e < 4; ++e) h[e] = f2bf(u[e]);
    *(u16x4*)(Wt + (size_t)(o0 + oo) * CC + c0) = h;
}

// ---------------------------------------------------------------------------
// Kernel 1: precompute via MFMA, no LDS (unchanged from R3-R6, verified).
// ---------------------------------------------------------------------------
__global__ __launch_bounds__(256) void precompute_kernel(
    const float* __restrict__ x, const float* __restrict__ W_fc,
    const float* __restrict__ b_fc, const u16* __restrict__ Wt,
    float* __restrict__ sj, float* __restrict__ sk, u16* __restrict__ Yt)
{
    const int t = threadIdx.x, l = t & 63, w = t >> 6;
    const int sl = l & 15, g = l >> 4;
    const int b  = blockIdx.x >> 6;
    const int k0 = (blockIdx.x & 63) << 5;
    const int mt = w & 1, nb = (w >> 1) << 2;
    const int row = k0 + mt * 16 + sl;
    const float* xr = x + ((size_t)(b * NN + row) << 7);

    bf16x8 a[4];
    float p1 = 0.f, p2 = 0.f;
    #pragma unroll
    for (int ks = 0; ks < 4; ++ks) {
        f32x4 lo4 = *(const f32x4*)(xr + ks * 32 + g * 8);
        f32x4 hi4 = *(const f32x4*)(xr + ks * 32 + g * 8 + 4);
        f32x4 w1l = *(const f32x4*)(W_fc + ks * 32 + g * 8);
        f32x4 w1h = *(const f32x4*)(W_fc + ks * 32 + g * 8 + 4);
        f32x4 w2l = *(const f32x4*)(W_fc + CC + ks * 32 + g * 8);
        f32x4 w2h = *(const f32x4*)(W_fc + CC + ks * 32 + g * 8 + 4);
        bf16x8 av;
        #pragma unroll
        for (int e = 0; e < 4; ++e) {
            p1 += lo4[e] * w1l[e] + hi4[e] * w1h[e];
            p2 += lo4[e] * w2l[e] + hi4[e] * w2h[e];
            av[e]     = (short)f2bf(lo4[e]);
            av[e + 4] = (short)f2bf(hi4[e]);
        }
        a[ks] = av;
    }
    p1 += __shfl_xor(p1, 16); p1 += __shfl_xor(p1, 32);
    p2 += __shfl_xor(p2, 16); p2 += __shfl_xor(p2, 32);
    if (w < 2 && g == 0) {
        sj[b * NN + row] = p1 + b_fc[0];
        sk[b * NN + row] = p2;
    }

    f32x4 acc[4];
    #pragma unroll
    for (int i = 0; i < 4; ++i) acc[i] = (f32x4){0.f, 0.f, 0.f, 0.f};
    #pragma unroll
    for (int i = 0; i < 4; ++i) {
        const u16* wp = Wt + (size_t)((nb + i) * 16 + sl) * CC;
        #pragma unroll
        for (int ks = 0; ks < 4; ++ks) {
            bf16x8 bv = *(const bf16x8*)(wp + ks * 32 + g * 8);
            acc[i] = __builtin_amdgcn_mfma_f32_16x16x32_bf16(a[ks], bv, acc[i], 0, 0, 0);
        }
    }
    #pragma unroll
    for (int i = 0; i < 4; ++i) {
        const int o = (nb + i) * 16 + sl;
        u16x4 h;
        #pragma unroll
        for (int e = 0; e < 4; ++e) h[e] = f2bf(acc[i][e]);
        *(u16x4*)(Yt + (size_t)(b * OO + o) * NN + k0 + mt * 16 + g * 4) = h;
    }
}

// ---------------------------------------------------------------------------
// Kernel 2: main aggregation — A-in-register + LDS-staged B, 1 barrier/tile.
//   - lane (sw,kg) computes ITS OWN A-fragment sigmoids (row sw of wave's
//     j16; k-slots kg) -> no pbuf, no ds_write, no P-sharing barrier
//   - B (Yt o64-slice) double-buffered in LDS via gl_lds (4 DMA/thread/tile),
//     amortized across the block's 4 waves; swizzled, conflict-free
//   - per tile: stage(t+1) FIRST, sigmoid(t), prefetch adj(t+2)/sk(t+1)
//     (static parity regs), 16 ds_read + 16 MFMA, vmcnt(12) + s_barrier
//   - rowsum pure-shuffle; LDS = 32KB only
// grid = 8b x 32jt x 2oh = 512 blocks x 256 thr; b = bid&7 XCD-pinned;
// o-half pairs adjacent in dispatch (adj L2 reuse). 8 waves/CU.
// ---------------------------------------------------------------------------
__global__ __launch_bounds__(256, 2) void graphconv_main(
    const int* __restrict__ adj, const float* __restrict__ sj,
    const float* __restrict__ sk, const u16* __restrict__ Yt,
    const float* __restrict__ b_lin, float* __restrict__ out)
{
    __shared__ __align__(16) u16 ybuf[2][8192];   // [par][64 o x 16 chunks x 8]

    const int t  = threadIdx.x;
    const int l  = t & 63, w = t >> 6;
    const int sw = l & 15, kg = l >> 4;
    const int b  = blockIdx.x & 7;
    const int rest = blockIdx.x >> 3;
    const int O0 = (rest & 1) << 6;          // o-half
    const int j0 = (rest >> 1) << 6;         // block j-base (64 rows)
    const int jrow = j0 + w * 16 + sw;       // this lane's P row

    const float sjr = sj[b * NN + jrow];
    const int*   arow = adj + ((size_t)b * NN + jrow) * NN + kg * 8;
    const float* skb  = sk + b * NN + kg * 8;

    // Y staging: linear LDS dest, inverse-swizzled per-lane global source
    u32 yoff[4];
    #pragma unroll
    for (int i = 0; i < 4; ++i) {
        int u  = (w * 4 + i) * 64 + l;
        int ol = u >> 4;
        int kc = (u & 15) ^ (ol & 15);
        yoff[i] = (u32)(b * OO + O0 + ol) * NN + kc * 8;
    }

    f32x4 acc[4];
    #pragma unroll
    for (int os = 0; os < 4; ++os) acc[os] = (f32x4){0.f, 0.f, 0.f, 0.f};
    float psum = 0.f;

    // static-parity prefetch sets: aE=adj(even), aO=adj(odd); s0/s1 = sk parity
    i32x4 aE[8], aO[8]; f32x4 s0[8], s1[8];
    #pragma unroll
    for (int kk = 0; kk < 4; ++kk) {
        aE[kk*2]   = *(const i32x4*)(arow + kk * 32);
        aE[kk*2+1] = *(const i32x4*)(arow + kk * 32 + 4);
        aO[kk*2]   = *(const i32x4*)(arow + 128 + kk * 32);
        aO[kk*2+1] = *(const i32x4*)(arow + 128 + kk * 32 + 4);
        s0[kk*2]   = *(const f32x4*)(skb + kk * 32);
        s0[kk*2+1] = *(const f32x4*)(skb + kk * 32 + 4);
    }
    // stage tile 0 LAST, then full drain (prologue only)
    #pragma unroll
    for (int i = 0; i < 4; ++i)
        gl_lds16(Yt + yoff[i], &ybuf[0][(w * 4 + i) * 512]);
    asm volatile("s_waitcnt vmcnt(0)" ::: "memory");
    __builtin_amdgcn_s_barrier();
    asm volatile("" ::: "memory");

#define SIGMOID_AF(A, SC)                                                     \
    bf16x8 af[4];                                                             \
    _Pragma("unroll")                                                         \
    for (int kk = 0; kk < 4; ++kk) {                                          \
        float pv[8];                                                          \
        _Pragma("unroll")                                                     \
        for (int h = 0; h < 2; ++h) {                                         \
            i32x4 a4 = A[kk * 2 + h];                                         \
            f32x4 s4 = SC[kk * 2 + h];                                        \
            _Pragma("unroll")                                                 \
            for (int e = 0; e < 4; ++e) {                                     \
                float z  = sjr + s4[e];                                       \
                float sg = __builtin_amdgcn_rcpf(1.0f + __expf(-z));          \
                float p  = a4[e] ? sg : 0.0f;                                 \
                psum += p;                                                    \
                pv[h * 4 + e] = p;                                            \
            }                                                                 \
        }                                                                     \
        af[kk] = __builtin_bit_cast(bf16x8,                                   \
            (u32x4){pkbf(pv[0], pv[1]), pkbf(pv[2], pv[3]),                   \
                    pkbf(pv[4], pv[5]), pkbf(pv[6], pv[7])});                 \
    }

#define MFMA_PHASE(PAR)                                                       \
    _Pragma("unroll")                                                         \
    for (int kk = 0; kk < 4; ++kk) {                                          \
        const int kc = kk * 4 + kg;                                           \
        _Pragma("unroll")                                                     \
        for (int os = 0; os < 4; ++os) {                                      \
            const int ol = os * 16 + sw;                                      \
            bf16x8 bv = *(const bf16x8*)&ybuf[PAR][(ol * 16 + (kc ^ sw)) * 8];\
            acc[os] = __builtin_amdgcn_mfma_f32_16x16x32_bf16(                \
                af[kk], bv, acc[os], 0, 0, 0);                                \
        }                                                                     \
    }

// full tile t (0..14): stage(t+1), sigmoid(t), prefetch adj(t+2)+sk(t+1),
// MFMA(t), vmcnt(12)+barrier. adj clamp at t=14 is a harmless redundant load
// (keeps the vmcnt count uniform).
#define TILE_BODY(T, A, SC, SN)                                               \
    {                                                                         \
        _Pragma("unroll")                                                     \
        for (int i = 0; i < 4; ++i)                                           \
            gl_lds16(Yt + yoff[i] + (((T) + 1) << 7),                         \
                     &ybuf[((T) + 1) & 1][(w * 4 + i) * 512]);                \
        SIGMOID_AF(A, SC)                                                     \
        {                                                                     \
            const int ta = ((T) + 2 > 15) ? 15 : (T) + 2;                     \
            _Pragma("unroll")                                                 \
            for (int kk = 0; kk < 4; ++kk) {                                  \
                A[kk*2]   = *(const i32x4*)(arow + ta * 128 + kk * 32);       \
                A[kk*2+1] = *(const i32x4*)(arow + ta * 128 + kk * 32 + 4);   \
                SN[kk*2]   = *(const f32x4*)(skb + ((T)+1) * 128 + kk * 32);  \
                SN[kk*2+1] = *(const f32x4*)(skb + ((T)+1) * 128 + kk * 32 + 4); \
            }                                                                 \
        }                                                                     \
        MFMA_PHASE((T) & 1)                                                   \
        asm volatile("s_waitcnt vmcnt(12)" ::: "memory");                     \
        __builtin_amdgcn_s_barrier();                                         \
        asm volatile("" ::: "memory");                                        \
    }

    for (int m = 0; m < 7; ++m) {          // tiles 0..13
        TILE_BODY(2 * m,     aE, s0, s1)
        TILE_BODY(2 * m + 1, aO, s1, s0)
    }
    TILE_BODY(14, aE, s0, s1)              // tile 14 (stages 15, loads sk15)
    {                                       // tail tile 15: no stage/prefetch
        SIGMOID_AF(aO, s1)
        MFMA_PHASE(1)
    }
#undef TILE_BODY
#undef MFMA_PHASE
#undef SIGMOID_AF

    // rowsum: lane (sw,kg) holds row sw's kg-slots -> reduce over kg
    float s = psum;
    s += __shfl_xor(s, 16);
    s += __shfl_xor(s, 32);                // every lane: S[row = l&15]
    float rinv[4];
    #pragma unroll
    for (int i = 0; i < 4; ++i)
        rinv[i] = 1.0f / __shfl(s, kg * 4 + i);

    // epilogue: C[j = j0 + w*16 + kg*4 + i][o = O0 + os*16 + sw]
    #pragma unroll
    for (int os = 0; os < 4; ++os) {
        const int col = O0 + os * 16 + sw;
        const float bl = b_lin[col];
        #pragma unroll
        for (int i = 0; i < 4; ++i)
            out[(size_t)(b * NN + j0 + w * 16 + kg * 4 + i) * OO + col] =
                acc[os][i] * rinv[i] + bl;
    }
}

extern "C" void kernel_launch(void* const* d_in, const int* in_sizes, int n_in,
                              void* d_out, int out_size, void* d_ws, size_t ws_size,
                              hipStream_t stream) {
    const float* x     = (const float*)d_in[0];
    const int*   adj   = (const int*)d_in[1];
    const float* W_fc  = (const float*)d_in[2];
    const float* b_fc  = (const float*)d_in[3];
    const float* W_lin = (const float*)d_in[4];
    const float* b_lin = (const float*)d_in[5];
    float* out = (float*)d_out;

    // workspace: Yt (bf16, 4MB) | sj (64KB) | sk (64KB) | Wt (32KB)
    u16*   Yt = (u16*)d_ws;
    float* sj = (float*)((char*)d_ws + (size_t)BB * OO * NN * sizeof(u16));
    float* sk = sj + BB * NN;
    u16*   Wt = (u16*)(sk + BB * NN);

    wt_kernel<<<16, 256, 0, stream>>>(W_lin, Wt);
    precompute_kernel<<<512, 256, 0, stream>>>(x, W_fc, b_fc, Wt, sj, sk, Yt);
    graphconv_main<<<512, 256, 0, stream>>>(adj, sj, sk, Yt, b_lin, out);
}

// Round 11
// 50.598 us; speedup vs baseline: 1.9513x; 1.3160x over previous
//
#include <hip/hip_runtime.h>
#include <stdint.h>

#define BB 8
#define NN 2048
#define CC 128
#define OO 128

typedef __attribute__((ext_vector_type(8))) short bf16x8;
typedef __attribute__((ext_vector_type(4))) float f32x4;
typedef __attribute__((ext_vector_type(4))) int i32x4;
typedef __attribute__((ext_vector_type(4))) unsigned short u16x4;
typedef unsigned int u32;
typedef unsigned short u16;

__device__ __forceinline__ u16 f2bf(float f) {
    union { float f; u32 u; } v; v.f = f;
    u32 r = v.u + 0x7FFFu + ((v.u >> 16) & 1u);
    return (u16)(r >> 16);
}

// async global->LDS 16B: LDS dest wave-uniform base + lane*16; swizzle lives
// in the per-lane global source address (m104/m173 rule).
__device__ __forceinline__ void gl_lds16(const u16* g, u16* l) {
    __builtin_amdgcn_global_load_lds(
        (__attribute__((address_space(1))) void*)(uintptr_t)g,
        (__attribute__((address_space(3))) void*)l, 16, 0, 0);
}

// ---------------------------------------------------------------------------
// Kernel 0: Wt[o][c] = bf16(W_lin[c][o]).  16 blocks x 256 thr (tiny).
// ---------------------------------------------------------------------------
__global__ __launch_bounds__(256) void wt_kernel(
    const float* __restrict__ W_lin, u16* __restrict__ Wt)
{
    __shared__ float ws2[8][132];
    const int t = threadIdx.x, o0 = blockIdx.x * 8;
    f32x4 v = *(const f32x4*)(W_lin + (t >> 1) * OO + o0 + (t & 1) * 4);
    #pragma unroll
    for (int e = 0; e < 4; ++e) ws2[(t & 1) * 4 + e][t >> 1] = v[e];
    __syncthreads();
    const int oo = t >> 5, c0 = (t & 31) * 4;
    f32x4 u = *(const f32x4*)&ws2[oo][c0];
    u16x4 h;
    #pragma unroll
    for (int e = 0; e < 4; ++e) h[e] = f2bf(u[e]);
    *(u16x4*)(Wt + (size_t)(o0 + oo) * CC + c0) = h;
}

// ---------------------------------------------------------------------------
// Kernel 1: precompute via MFMA, no LDS.
//   sj[b][n] = x·w1 + b_fc ; sk[b][n] = x·w2 (f32); Yt = bf16((x@W_lin)^T)
// ---------------------------------------------------------------------------
__global__ __launch_bounds__(256) void precompute_kernel(
    const float* __restrict__ x, const float* __restrict__ W_fc,
    const float* __restrict__ b_fc, const u16* __restrict__ Wt,
    float* __restrict__ sj, float* __restrict__ sk, u16* __restrict__ Yt)
{
    const int t = threadIdx.x, l = t & 63, w = t >> 6;
    const int sl = l & 15, g = l >> 4;
    const int b  = blockIdx.x >> 6;
    const int k0 = (blockIdx.x & 63) << 5;
    const int mt = w & 1, nb = (w >> 1) << 2;
    const int row = k0 + mt * 16 + sl;
    const float* xr = x + ((size_t)(b * NN + row) << 7);

    bf16x8 a[4];
    float p1 = 0.f, p2 = 0.f;
    #pragma unroll
    for (int ks = 0; ks < 4; ++ks) {
        f32x4 lo4 = *(const f32x4*)(xr + ks * 32 + g * 8);
        f32x4 hi4 = *(const f32x4*)(xr + ks * 32 + g * 8 + 4);
        f32x4 w1l = *(const f32x4*)(W_fc + ks * 32 + g * 8);
        f32x4 w1h = *(const f32x4*)(W_fc + ks * 32 + g * 8 + 4);
        f32x4 w2l = *(const f32x4*)(W_fc + CC + ks * 32 + g * 8);
        f32x4 w2h = *(const f32x4*)(W_fc + CC + ks * 32 + g * 8 + 4);
        bf16x8 av;
        #pragma unroll
        for (int e = 0; e < 4; ++e) {
            p1 += lo4[e] * w1l[e] + hi4[e] * w1h[e];
            p2 += lo4[e] * w2l[e] + hi4[e] * w2h[e];
            av[e]     = (short)f2bf(lo4[e]);
            av[e + 4] = (short)f2bf(hi4[e]);
        }
        a[ks] = av;
    }
    p1 += __shfl_xor(p1, 16); p1 += __shfl_xor(p1, 32);
    p2 += __shfl_xor(p2, 16); p2 += __shfl_xor(p2, 32);
    if (w < 2 && g == 0) {
        sj[b * NN + row] = p1 + b_fc[0];
        sk[b * NN + row] = p2;
    }

    f32x4 acc[4];
    #pragma unroll
    for (int i = 0; i < 4; ++i) acc[i] = (f32x4){0.f, 0.f, 0.f, 0.f};
    #pragma unroll
    for (int i = 0; i < 4; ++i) {
        const u16* wp = Wt + (size_t)((nb + i) * 16 + sl) * CC;
        #pragma unroll
        for (int ks = 0; ks < 4; ++ks) {
            bf16x8 bv = *(const bf16x8*)(wp + ks * 32 + g * 8);
            acc[i] = __builtin_amdgcn_mfma_f32_16x16x32_bf16(a[ks], bv, acc[i], 0, 0, 0);
        }
    }
    #pragma unroll
    for (int i = 0; i < 4; ++i) {
        const int o = (nb + i) * 16 + sl;
        u16x4 h;
        #pragma unroll
        for (int e = 0; e < 4; ++e) h[e] = f2bf(acc[i][e]);
        *(u16x4*)(Yt + (size_t)(b * OO + o) * NN + k0 + mt * 16 + g * 4) = h;
    }
}

// ---------------------------------------------------------------------------
// Kernel 2: main fused aggregation. Lane-contiguous adj loads, 2-deep adj/sk
// prefetch, counted vmcnt(18), double-buffered Y staging.
//   P[j][k] = adj ? sigmoid(sj[j]+sk[k]) : 0 (bf16); V = P@Y^T (MFMA);
//   out = V/rowsum + b_lin
// 512 blocks (b = bid&7 -> XCD-pinned), 256 thr / 4 waves; j-tile 32, K 128.
// VMEM/iter = 8 stage + 4 adj + 1 sk = 13; stage(kt) has 18 younger ops at
// the wait point -> vmcnt(18).
// [R3 baseline, benched 50.935us / absmax 9.77e-4 — kept VERBATIM]
// ---------------------------------------------------------------------------
__global__ __launch_bounds__(256, 2) void graphconv_main(
    const int* __restrict__ adj, const float* __restrict__ sj,
    const float* __restrict__ sk, const u16* __restrict__ Yt,
    const float* __restrict__ b_lin, float* __restrict__ out)
{
    __shared__ __align__(16) u16 ybuf[2][16384];  // 2 x (128 o x 16 chunks x 8)
    __shared__ __align__(16) u16 pbuf[4096];      // 32 j x 16 chunks x 8
    __shared__ float Sld[32];

    const int t  = threadIdx.x;
    const int l  = t & 63, w = t >> 6;
    const int sw = l & 15, kg = l >> 4;
    const int lo = l & 31, hi = l >> 5;
    const int b  = blockIdx.x & 7;
    const int j0 = (blockIdx.x >> 3) << 5;

    // P-phase mapping: instr q covers rows w*8+2q+hi, lane-contiguous 16B
    const int* arow[4];
    float sjr[4];
    #pragma unroll
    for (int q = 0; q < 4; ++q) {
        const int R = j0 + w * 8 + 2 * q + hi;
        arow[q] = adj + ((size_t)b * NN + R) * NN + lo * 4;
        sjr[q]  = sj[b * NN + R];
    }
    const float* skp = sk + b * NN + lo * 4;

    // Y staging: linear LDS dest, inverse-swizzled per-lane global source
    u32 yoff[8];
    #pragma unroll
    for (int i = 0; i < 8; ++i) {
        int u  = (w * 8 + i) * 64 + l;
        int o  = u >> 4;
        int kc = (u & 15) ^ (o & 15);
        yoff[i] = (u32)(b * OO + o) * NN + kc * 8;
    }

    f32x4 acc[2][2];
    #pragma unroll
    for (int js = 0; js < 2; ++js)
        #pragma unroll
        for (int os = 0; os < 2; ++os) acc[js][os] = (f32x4){0.f, 0.f, 0.f, 0.f};
    float psum[4] = {0.f, 0.f, 0.f, 0.f};

    // prologue: stage(0) [8] + adj/sk(0) [5] + adj/sk(1) [5]
    #pragma unroll
    for (int i = 0; i < 8; ++i)
        gl_lds16(Yt + yoff[i], &ybuf[0][(w * 8 + i) * 512]);
    i32x4 a_cur[4], a_n1[4];
    f32x4 s_cur, s_n1;
    #pragma unroll
    for (int q = 0; q < 4; ++q) a_cur[q] = *(const i32x4*)(arow[q]);
    s_cur = *(const f32x4*)(skp);
    #pragma unroll
    for (int q = 0; q < 4; ++q) a_n1[q] = *(const i32x4*)(arow[q] + 128);
    s_n1 = *(const f32x4*)(skp + 128);

    for (int kt = 0; kt < 16; ++kt) {
        const int cur = kt & 1;
        const int kt1 = (kt < 15) ? kt + 1 : 15;  // tail re-stage: idempotent
        const int kt2 = (kt < 14) ? kt + 2 : 15;  // keeps vmcnt count uniform
        // stage next Y tile (in flight across this whole iteration)
        #pragma unroll
        for (int i = 0; i < 8; ++i)
            gl_lds16(Yt + yoff[i] + (kt1 << 7), &ybuf[cur ^ 1][(w * 8 + i) * 512]);
        // 2-deep adj/sk prefetch
        i32x4 a_n2[4]; f32x4 s_n2;
        #pragma unroll
        for (int q = 0; q < 4; ++q) a_n2[q] = *(const i32x4*)(arow[q] + kt2 * 128);
        s_n2 = *(const f32x4*)(skp + kt2 * 128);

        // P = masked sigmoid; per-thread rowsum accumulates in registers
        u16x4 hq[4];
        #pragma unroll
        for (int q = 0; q < 4; ++q) {
            #pragma unroll
            for (int e = 0; e < 4; ++e) {
                float z  = sjr[q] + s_cur[e];
                float sg = __builtin_amdgcn_rcpf(1.0f + __expf(-z));
                float pv = a_cur[q][e] ? sg : 0.0f;
                psum[q] += pv;
                hq[q][e] = f2bf(pv);
            }
        }
        {
            const int kc = lo >> 1, hh = lo & 1;
            #pragma unroll
            for (int q = 0; q < 4; ++q) {
                const int R = w * 8 + 2 * q + hi;
                const int u = R * 16 + (kc ^ (R & 15));
                *(u16x4*)&pbuf[u * 8 + hh * 4] = hq[q];
            }
        }

        // counted drain: stage(kt) complete, 18 younger ops stay in flight
        asm volatile("s_waitcnt vmcnt(18)" ::: "memory");
        asm volatile("s_waitcnt lgkmcnt(0)" ::: "memory");
        __builtin_amdgcn_s_barrier();
        asm volatile("" ::: "memory");

        // MFMA: wave w -> j 0..31 x o [w*32, w*32+32)
        #pragma unroll
        for (int kk = 0; kk < 4; ++kk) {
            const int kc = kk * 4 + kg;
            bf16x8 af[2], bfr[2];
            #pragma unroll
            for (int js = 0; js < 2; ++js)
                af[js] = *(const bf16x8*)&pbuf[((js * 16 + sw) * 16 + (kc ^ sw)) * 8];
            #pragma unroll
            for (int os = 0; os < 2; ++os) {
                int o = w * 32 + os * 16 + sw;
                bfr[os] = *(const bf16x8*)&ybuf[cur][(o * 16 + (kc ^ sw)) * 8];
            }
            #pragma unroll
            for (int js = 0; js < 2; ++js)
                #pragma unroll
                for (int os = 0; os < 2; ++os)
                    acc[js][os] = __builtin_amdgcn_mfma_f32_16x16x32_bf16(
                        af[js], bfr[os], acc[js][os], 0, 0, 0);
        }

        asm volatile("" ::: "memory");
        __builtin_amdgcn_s_barrier();   // MFMA LDS reads done before next writes
        asm volatile("" ::: "memory");

        #pragma unroll
        for (int q = 0; q < 4; ++q) a_cur[q] = a_n1[q];
        s_cur = s_n1;
        #pragma unroll
        for (int q = 0; q < 4; ++q) a_n1[q] = a_n2[q];
        s_n1 = s_n2;
    }

    // rowsum reduce (once): rows' 128 k live across 32 lanes (same hi)
    #pragma unroll
    for (int q = 0; q < 4; ++q) {
        float s = psum[q];
        s += __shfl_xor(s, 1); s += __shfl_xor(s, 2); s += __shfl_xor(s, 4);
        s += __shfl_xor(s, 8); s += __shfl_xor(s, 16);
        if (lo == 0) Sld[w * 8 + 2 * q + hi] = s;
    }
    __syncthreads();   // also drains tail junk DMA (vmcnt 0) before LDS reuse ends

    #pragma unroll
    for (int js = 0; js < 2; ++js) {
        float rinv[4];
        #pragma unroll
        for (int i = 0; i < 4; ++i) rinv[i] = 1.0f / Sld[js * 16 + kg * 4 + i];
        #pragma unroll
        for (int os = 0; os < 2; ++os) {
            const int col = w * 32 + os * 16 + sw;
            const float bl = b_lin[col];
            #pragma unroll
            for (int i = 0; i < 4; ++i) {
                size_t row = (size_t)(b * NN + j0 + js * 16 + kg * 4 + i);
                out[row * OO + col] = acc[js][os][i] * rinv[i] + bl;
            }
        }
    }
}

extern "C" void kernel_launch(void* const* d_in, const int* in_sizes, int n_in,
                              void* d_out, int out_size, void* d_ws, size_t ws_size,
                              hipStream_t stream) {
    const float* x     = (const float*)d_in[0];
    const int*   adj   = (const int*)d_in[1];
    const float* W_fc  = (const float*)d_in[2];
    const float* b_fc  = (const float*)d_in[3];
    const float* W_lin = (const float*)d_in[4];
    const float* b_lin = (const float*)d_in[5];
    float* out = (float*)d_out;

    // workspace: Yt (bf16, 4MB) | sj (64KB) | sk (64KB) | Wt (32KB)
    u16*   Yt = (u16*)d_ws;
    float* sj = (float*)((char*)d_ws + (size_t)BB * OO * NN * sizeof(u16));
    float* sk = sj + BB * NN;
    u16*   Wt = (u16*)(sk + BB * NN);

    wt_kernel<<<16, 256, 0, stream>>>(W_lin, Wt);
    precompute_kernel<<<512, 256, 0, stream>>>(x, W_fc, b_fc, Wt, sj, sk, Yt);
    graphconv_main<<<512, 256, 0, stream>>>(adj, sj, sk, Yt, b_lin, out);
}